// Round 1
// baseline (233.314 us; speedup 1.0000x reference)
//
#include <hip/hip_runtime.h>
#include <stdint.h>

typedef unsigned long long u64;
typedef unsigned int u32;

#define BATCH 64
#define NANCH 8732
#define NCLS 21
#define KCAND 200
#define KPAD 256
#define PPC 20
#define PTOT 20

// -------------------- Kernel A: argmax mask + decode + transpose --------------------
__global__ __launch_bounds__(256) void kdecode(
    const float* __restrict__ deltas, const float* __restrict__ labels,
    const float* __restrict__ anchors, float* __restrict__ boxes,
    unsigned char* __restrict__ msk, float* __restrict__ scoresT, int useT)
{
#pragma clang fp contract(off)
    int n = blockIdx.x * 256 + threadIdx.x;
    int b = blockIdx.y;
    if (n >= NANCH) return;
    const float* lab = labels + ((size_t)b * NANCH + n) * NCLS;
    float v[NCLS];
#pragma unroll
    for (int c = 0; c < NCLS; ++c) v[c] = lab[c];
    float mx = v[0]; int am = 0;
#pragma unroll
    for (int c = 1; c < NCLS; ++c) if (v[c] > mx) { mx = v[c]; am = c; }
    bool mk = (am != 0);
    msk[(size_t)b * NANCH + n] = mk ? 1 : 0;
    if (useT) {
#pragma unroll
        for (int c = 0; c < NCLS; ++c)
            scoresT[((size_t)b * NCLS + c) * NANCH + n] = mk ? v[c] : 0.0f;
    }
    float4 d = ((const float4*)deltas)[(size_t)b * NANCH + n];
    float4 a = ((const float4*)anchors)[n];
    float ah = a.z - a.x, aw = a.w - a.y;
    float acy = a.x + 0.5f * ah, acx = a.y + 0.5f * aw;
    float cy = (d.x * 0.1f) * ah + acy;
    float cx = (d.y * 0.1f) * aw + acx;
    float hh = expf(d.z * 0.2f) * ah;
    float ww = expf(d.w * 0.2f) * aw;
    float4 o;
    o.x = cy - 0.5f * hh; o.y = cx - 0.5f * ww;
    o.z = cy + 0.5f * hh; o.w = cx + 0.5f * ww;
    ((float4*)boxes)[(size_t)b * NANCH + n] = o;
}

// bitonic sort, descending by u64 key, n power of two, blockDim.x >= n
__device__ __forceinline__ void bsortDesc(u64* key, int n, int tid)
{
    for (int k = 2; k <= n; k <<= 1)
        for (int j = k >> 1; j > 0; j >>= 1) {
            __syncthreads();
            int ixj = tid ^ j;
            if (tid < n && ixj > tid && ixj < n) {
                u64 a = key[tid], bb = key[ixj];
                if (((tid & k) == 0) ? (a < bb) : (a > bb)) { key[tid] = bb; key[ixj] = a; }
            }
        }
    __syncthreads();
}

// -------------------- Kernel B: per (b,c) top-200 + NMS + top-20 --------------------
__global__ __launch_bounds__(256) void knms(
    const float* __restrict__ labels, const unsigned char* __restrict__ msk,
    const float* __restrict__ scoresT, const float* __restrict__ boxes,
    float* __restrict__ clsScores, float* __restrict__ clsBoxes, int useT)
{
#pragma clang fp contract(off)
    __shared__ float sv[NANCH];
    __shared__ u32 hist[256];
    __shared__ int sSel, sAbove, sNgt, sBufCnt;
    __shared__ u64 bufKey[256];
    __shared__ u64 candKey[KPAD];
    __shared__ float cbY1[KPAD], cbX1[KPAD], cbY2[KPAD], cbX2[KPAD], cbAr[KPAD], cVal[KPAD];
    __shared__ u64 iouM[KCAND][4];
    __shared__ float outS[PPC];
    __shared__ float outB[PPC * 4];

    const int tid = threadIdx.x;
    const int bc = blockIdx.x;
    const int b = bc / NCLS;
    const int c = bc % NCLS;

    // ---- load masked scores into LDS ----
    if (useT) {
        const float* src = scoresT + (size_t)bc * NANCH;
        for (int n = tid; n < NANCH; n += 256) sv[n] = src[n];
    } else {
        for (int n = tid; n < NANCH; n += 256) {
            float val = labels[((size_t)b * NANCH + n) * NCLS + c];
            sv[n] = msk[(size_t)b * NANCH + n] ? val : 0.0f;
        }
    }
    __syncthreads();

    // ---- radix-select 200th largest on t = trunc(v * 2^24) (monotone in v) ----
    int need = KCAND;
    u32 tpref = 0, tmask = 0;
    for (int pass = 0; pass < 3; ++pass) {
        int shift = 16 - 8 * pass;
        hist[tid] = 0;
        __syncthreads();
        for (int n = tid; n < NANCH; n += 256) {
            u32 t = (u32)(sv[n] * 16777216.0f);
            if ((t & tmask) == tpref) atomicAdd(&hist[(t >> shift) & 255u], 1u);
        }
        __syncthreads();
        if (tid == 0) {
            int cum = 0, sel = 0, above = 0;
            for (int bin = 255; bin >= 0; --bin) {
                int h = (int)hist[bin];
                if (cum + h >= need) { sel = bin; above = cum; break; }
                cum += h;
            }
            sSel = sel; sAbove = above;
        }
        __syncthreads();
        need -= sAbove;
        tpref |= ((u32)sSel) << shift;
        tmask |= 255u << shift;
    }
    const u32 T = tpref;
    const int cntGT = KCAND - need;   // exact count of t > T

    // ---- compaction: >T into candKey slots, ==T into tie buffer ----
    if (tid == 0) { sNgt = 0; sBufCnt = 0; }
    __syncthreads();
    for (int n = tid; n < NANCH; n += 256) {
        float v = sv[n];
        u32 t = (u32)(v * 16777216.0f);
        if (t > T) {
            int slot = atomicAdd(&sNgt, 1);
            candKey[slot] = ((u64)__float_as_uint(v) << 32) | (u32)(~(u32)n);
        } else if (t == T) {
            int slot = atomicAdd(&sBufCnt, 1);
            if (slot < 256) bufKey[slot] = ((u64)__float_as_uint(v) << 32) | (u32)(~(u32)n);
        }
    }
    __syncthreads();
    int bcnt = sBufCnt; if (bcnt > 256) bcnt = 256;
    if (tid >= bcnt) bufKey[tid] = 0;
    bsortDesc(bufKey, 256, tid);
    if (tid < need) candKey[cntGT + tid] = bufKey[tid];
    if (tid >= KCAND) candKey[tid] = 0;
    bsortDesc(candKey, KPAD, tid);   // exact top_k order: value desc, index asc

    // ---- extract candidates, gather boxes ----
    {
        u64 kk = candKey[tid];
        float v = __uint_as_float((u32)(kk >> 32));
        cVal[tid] = (tid < KCAND) ? v : 0.0f;
        float4 bx = make_float4(0.f, 0.f, 0.f, 0.f);
        if (tid < KCAND) {
            u32 idx = ~((u32)kk);
            bx = ((const float4*)boxes)[(size_t)b * NANCH + idx];
        }
        cbY1[tid] = bx.x; cbX1[tid] = bx.y; cbY2[tid] = bx.z; cbX2[tid] = bx.w;
        cbAr[tid] = (bx.z - bx.x) * (bx.w - bx.y);
    }
    __syncthreads();

    // ---- 200x200 IoU bitmask via per-wave ballot ----
    const int lane = tid & 63;
    const int wv = tid >> 6;
    for (int i = 0; i < KCAND; ++i) {
        float y1i = cbY1[i], x1i = cbX1[i], y2i = cbY2[i], x2i = cbX2[i], ari = cbAr[i];
        bool hit = false;
        if (tid < KCAND) {
            float ih = fminf(y2i, cbY2[tid]) - fmaxf(y1i, cbY1[tid]);
            ih = fmaxf(ih, 0.0f);
            float iw = fminf(x2i, cbX2[tid]) - fmaxf(x1i, cbX1[tid]);
            iw = fmaxf(iw, 0.0f);
            float inter = ih * iw;
            float iou = inter / (ari + cbAr[tid] - inter + 1e-8f);
            hit = iou > 0.5f;
        }
        u64 bal = __ballot(hit);
        if (lane == 0) iouM[i][wv] = bal;
    }
    __syncthreads();

    if (tid < PPC) outS[tid] = 0.0f;
    if (tid < PPC * 4) outB[tid] = 0.0f;
    __syncthreads();

    // ---- sequential NMS, 64-lane cooperative (wave 0) ----
    if (tid < 64) {
        u64 k0 = 0, k1 = 0, k2 = 0, k3 = 0;
#pragma unroll
        for (int chunk = 0; chunk < 4; ++chunk) {
            int i = chunk * 64 + tid;
            u64 r0 = 0, r1 = 0, r2 = 0, r3 = 0;
            bool vld = false;
            if (i < KCAND) {
                r0 = iouM[i][0]; r1 = iouM[i][1]; r2 = iouM[i][2]; r3 = iouM[i][3];
                vld = cVal[i] > 0.5f;
            }
            int lim = KCAND - chunk * 64; if (lim > 64) lim = 64; if (lim < 0) lim = 0;
            for (int l = 0; l < lim; ++l) {
                // keep-mask only has bits of already-processed (smaller) indices,
                // so (keep & row) implicitly enforces j < i
                int mydec = (vld && !((k0 & r0) | (k1 & r1) | (k2 & r2) | (k3 & r3))) ? 1 : 0;
                int d = __shfl(mydec, l, 64);
                if (d) {
                    u64 bit = 1ull << l;
                    if (chunk == 0) k0 |= bit; else if (chunk == 1) k1 |= bit;
                    else if (chunk == 2) k2 |= bit; else k3 |= bit;
                }
            }
        }
        // ---- emit first 20 kept (== top_k(kept_scores, 20) since values sorted) ----
        int base = 0;
#pragma unroll
        for (int chunk = 0; chunk < 4; ++chunk) {
            u64 kw = (chunk == 0) ? k0 : (chunk == 1) ? k1 : (chunk == 2) ? k2 : k3;
            int i = chunk * 64 + tid;
            bool kept = ((kw >> tid) & 1ull) != 0;
            int rank = base + (int)__popcll(kw & ((1ull << tid) - 1ull));
            if (kept && rank < PPC && i < KCAND) {
                outS[rank] = cVal[i];
                outB[rank * 4 + 0] = cbY1[i];
                outB[rank * 4 + 1] = cbX1[i];
                outB[rank * 4 + 2] = cbY2[i];
                outB[rank * 4 + 3] = cbX2[i];
            }
            base += (int)__popcll(kw);
        }
    }
    __syncthreads();
    if (tid < PPC) clsScores[(size_t)bc * PPC + tid] = outS[tid];
    if (tid < PPC * 4) clsBoxes[(size_t)bc * PPC * 4 + tid] = outB[tid];
}

// -------------------- Kernel C: merge 21*20 per batch -> top 20 --------------------
__global__ __launch_bounds__(512) void kmerge(
    const float* __restrict__ clsScores, const float* __restrict__ clsBoxes,
    float* __restrict__ out)
{
#pragma clang fp contract(off)
    __shared__ u64 key[512];
    const int tid = threadIdx.x;
    const int b = blockIdx.x;
    const int F = NCLS * PPC;  // 420
    u64 kk = 0;
    if (tid < F) {
        float v = clsScores[(size_t)b * F + tid];
        kk = ((u64)__float_as_uint(v) << 32) | (u32)(~(u32)tid);
    }
    key[tid] = kk;
    bsortDesc(key, 512, tid);
    if (tid < PTOT) {
        u64 kx = key[tid];
        float v = __uint_as_float((u32)(kx >> 32));
        u32 f = ~((u32)kx);
        bool valid = (v > 0.0f) && (f < (u32)F);
        float cls = valid ? (float)(f / PPC) : 0.0f;
        float* oB = out;
        float* oV = out + (size_t)BATCH * PTOT * 4;
        float* oL = oV + (size_t)BATCH * PTOT;
#pragma unroll
        for (int q = 0; q < 4; ++q) {
            float x = 0.0f;
            if (valid) {
                x = clsBoxes[((size_t)b * F + f) * 4 + q];
                x = fminf(fmaxf(x, 0.0f), 1.0f);
            }
            oB[((size_t)b * PTOT + tid) * 4 + q] = x;
        }
        oV[(size_t)b * PTOT + tid] = v;
        oL[(size_t)b * PTOT + tid] = cls;
    }
}

extern "C" void kernel_launch(void* const* d_in, const int* in_sizes, int n_in,
                              void* d_out, int out_size, void* d_ws, size_t ws_size,
                              hipStream_t stream)
{
    const float* deltas  = (const float*)d_in[0];
    const float* labels  = (const float*)d_in[1];
    const float* anchors = (const float*)d_in[2];
    float* out = (float*)d_out;
    char* ws = (char*)d_ws;

    // ws layout (all offsets 256B aligned)
    const size_t boxesOff = 0;           // B*N*4 f32 = 8,941,568 B
    const size_t maskOff  = 8941568;     // B*N u8   =   558,848 B
    const size_t csOff    = 9500416;     // B*C*20 f32 = 107,520 B
    const size_t cbOff    = 9607936;     // B*C*20*4 f32 = 430,080 B
    const size_t stOff    = 10038016;    // B*C*N f32 = 46,943,232 B (optional)
    const size_t needT    = 56981248;

    float* boxes = (float*)(ws + boxesOff);
    unsigned char* msk = (unsigned char*)(ws + maskOff);
    float* clsScores = (float*)(ws + csOff);
    float* clsBoxes  = (float*)(ws + cbOff);
    float* scoresT   = (float*)(ws + stOff);
    int useT = (ws_size >= needT) ? 1 : 0;
    if (!useT) scoresT = boxes;  // unused in that case

    dim3 gA((NANCH + 255) / 256, BATCH);
    kdecode<<<gA, 256, 0, stream>>>(deltas, labels, anchors, boxes, msk, scoresT, useT);
    knms<<<BATCH * NCLS, 256, 0, stream>>>(labels, msk, scoresT, boxes, clsScores, clsBoxes, useT);
    kmerge<<<BATCH, 512, 0, stream>>>(clsScores, clsBoxes, out);
}

// Round 2
// 144.148 us; speedup vs baseline: 1.6186x; 1.6186x over previous
//
#include <hip/hip_runtime.h>
#include <stdint.h>

typedef unsigned long long u64;
typedef unsigned int u32;

#define BATCH 64
#define NANCH 8732
#define NCLS 21
#define KCAND 200
#define PPC 20
#define PTOT 20

// -------------------- Kernel A: argmax mask + decode + transpose --------------------
__global__ __launch_bounds__(256) void kdecode(
    const float* __restrict__ deltas, const float* __restrict__ labels,
    const float* __restrict__ anchors, float* __restrict__ boxes,
    unsigned char* __restrict__ msk, float* __restrict__ scoresT, int useT)
{
#pragma clang fp contract(off)
    int n = blockIdx.x * 256 + threadIdx.x;
    int b = blockIdx.y;
    if (n >= NANCH) return;
    const float* lab = labels + ((size_t)b * NANCH + n) * NCLS;
    float v[NCLS];
#pragma unroll
    for (int c = 0; c < NCLS; ++c) v[c] = lab[c];
    float mx = v[0]; int am = 0;
#pragma unroll
    for (int c = 1; c < NCLS; ++c) if (v[c] > mx) { mx = v[c]; am = c; }
    bool mk = (am != 0);
    msk[(size_t)b * NANCH + n] = mk ? 1 : 0;
    if (useT) {
#pragma unroll
        for (int c = 0; c < NCLS; ++c)
            scoresT[((size_t)b * NCLS + c) * NANCH + n] = mk ? v[c] : 0.0f;
    }
    float4 d = ((const float4*)deltas)[(size_t)b * NANCH + n];
    float4 a = ((const float4*)anchors)[n];
    float ah = a.z - a.x, aw = a.w - a.y;
    float acy = a.x + 0.5f * ah, acx = a.y + 0.5f * aw;
    float cy = (d.x * 0.1f) * ah + acy;
    float cx = (d.y * 0.1f) * aw + acx;
    float hh = expf(d.z * 0.2f) * ah;
    float ww = expf(d.w * 0.2f) * aw;
    float4 o;
    o.x = cy - 0.5f * hh; o.y = cx - 0.5f * ww;
    o.z = cy + 0.5f * hh; o.w = cx + 0.5f * ww;
    ((float4*)boxes)[(size_t)b * NANCH + n] = o;
}

__device__ __forceinline__ u64 shflxor64(u64 x, int m) {
    return (u64)__shfl_xor((long long)x, m, 64);
}

// Parallel "find bin where descending cumulative count crosses `need`".
// hist has nb bins (nb <= 2048); writes sSel (bin), sAbove (count strictly above), sH (bin count).
__device__ __forceinline__ void suffixFind(u32* hist, u32* scratch, int nb, int need,
                                           int* sSel, int* sAbove, int* sH, int tid)
{
    if (tid == 0) { *sSel = 0; *sAbove = 0; *sH = 0; }
    int K = (nb + 255) >> 8;          // bins per thread (8 or 1)
    int base = tid * K;
    u32 s = 0;
    for (int q = 0; q < K; ++q) { int bi = base + q; s += (bi < nb) ? hist[bi] : 0u; }
    scratch[tid] = s;
    __syncthreads();
    // inclusive suffix sum over 256 thread-sums (Hillis-Steele)
    for (int d = 1; d < 256; d <<= 1) {
        u32 vv = scratch[tid] + ((tid + d < 256) ? scratch[tid + d] : 0u);
        __syncthreads();
        scratch[tid] = vv;
        __syncthreads();
    }
    u32 cum = (tid < 255) ? scratch[tid + 1] : 0u;   // strictly-higher threads
    for (int q = K - 1; q >= 0; --q) {               // own bins, high -> low
        int bi = base + q;
        u32 hh = (bi < nb) ? hist[bi] : 0u;
        if (cum < (u32)need && cum + hh >= (u32)need) { *sSel = bi; *sAbove = (int)cum; *sH = (int)hh; }
        cum += hh;
    }
    __syncthreads();
}

// -------------------- Kernel B: per (b,c) top-200 + NMS + top-20 --------------------
__global__ __launch_bounds__(256, 8) void knms(
    const float* __restrict__ labels, const unsigned char* __restrict__ msk,
    const float* __restrict__ scoresT, const float* __restrict__ boxes,
    float* __restrict__ clsScores, float* __restrict__ clsBoxes, int useT)
{
#pragma clang fp contract(off)
    // Region union: hist[2048] (selection phase) overlays cb*/cVal/iouM (post phase)
    __shared__ __align__(16) char smem[12544];
    u32*   hist = (u32*)smem;                 // [2048], selection only
    float* cbY1 = (float*)smem;               // [256]
    float* cbX1 = (float*)(smem + 1024);
    float* cbY2 = (float*)(smem + 2048);
    float* cbX2 = (float*)(smem + 3072);
    float* cbAr = (float*)(smem + 4096);
    float* cVal = (float*)(smem + 5120);
    u64*   iouM = (u64*)(smem + 6144);        // [200*4]
    __shared__ u32 scratch[256];
    __shared__ u64 candKey[256];
    __shared__ float outS[PPC];
    __shared__ float outB[PPC * 4];
    __shared__ int sSel, sAbove, sH, sN;

    const int tid = threadIdx.x;
    const int bc = blockIdx.x;
    const int b = bc / NCLS;
    const int c = bc % NCLS;
    const float* srcT = scoresT + (size_t)bc * NANCH;

#define FETCH_SCORE(n, v)                                                        \
    do {                                                                         \
        if (useT) v = srcT[(n)];                                                 \
        else {                                                                   \
            float vv_ = labels[((size_t)b * NANCH + (n)) * NCLS + c];            \
            v = msk[(size_t)b * NANCH + (n)] ? vv_ : 0.0f;                       \
        }                                                                        \
    } while (0)

    // ---- scan 1: 2048-bin histogram of t>>13, t = trunc(v * 2^24) ----
    for (int q = tid; q < 2048; q += 256) hist[q] = 0;
    __syncthreads();
    for (int n = tid; n < NANCH; n += 256) {
        float v; FETCH_SCORE(n, v);
        u32 t = (u32)(v * 16777216.0f);
        atomicAdd(&hist[t >> 13], 1u);
    }
    __syncthreads();
    suffixFind(hist, scratch, 2048, KCAND, &sSel, &sAbove, &sH, tid);
    int A = sAbove, h = sH;
    u32 T = (u32)sSel << 13;
    int cnt = A + h;

    // ---- exact refinement if threshold bin overflows 256-key buffer (practically never) ----
    u32 width = 8192;
    for (int level = 0; level < 2 && cnt > 256; ++level) {
        int nb = (level == 0) ? 256 : 32;
        int shift = (level == 0) ? 5 : 0;
        if (tid < nb) hist[tid] = 0;
        __syncthreads();
        for (int n = tid; n < NANCH; n += 256) {
            float v; FETCH_SCORE(n, v);
            u32 t = (u32)(v * 16777216.0f);
            if (t >= T && t - T < width) atomicAdd(&hist[(t - T) >> shift], 1u);
        }
        __syncthreads();
        suffixFind(hist, scratch, nb, KCAND - A, &sSel, &sAbove, &sH, tid);
        h = sH;
        A += sAbove;
        T += (u32)sSel << shift;
        cnt = A + h;
        width = 1u << shift;
    }

    // ---- scan 2: compact all t >= T (superset of exact top-200 incl. all value ties) ----
    if (tid == 0) sN = 0;
    __syncthreads();
    for (int n = tid; n < NANCH; n += 256) {
        float v; FETCH_SCORE(n, v);
        u32 t = (u32)(v * 16777216.0f);
        if (t >= T) {
            int slot = atomicAdd(&sN, 1);
            if (slot < 256) candKey[slot] = ((u64)__float_as_uint(v) << 32) | (u32)(~(u32)n);
        }
    }
    __syncthreads();
    int nc = sN; if (nc > 256) nc = 256;

    // ---- register bitonic sort desc on 256 keys (shfl_xor for j<64, LDS for j>=64) ----
    u64 x = (tid < nc) ? candKey[tid] : 0ull;
    for (int k = 2; k <= 256; k <<= 1) {
        for (int j = k >> 1; j > 0; j >>= 1) {
            u64 y;
            if (j < 64) {
                y = shflxor64(x, j);
            } else {
                __syncthreads();
                candKey[tid] = x;
                __syncthreads();
                y = candKey[tid ^ j];
            }
            bool keepMax = ((tid & k) == 0) == ((tid & j) == 0);
            u64 mx = (x > y) ? x : y;
            u64 mn = (x > y) ? y : x;
            x = keepMax ? mx : mn;
        }
    }
    // x = tid-th largest key (value desc, index asc) == top_k order; tid<200 always real.

    // ---- extract + gather boxes (own candidate stays in registers) ----
    float myV = __uint_as_float((u32)(x >> 32));
    float myY1 = 0.f, myX1 = 0.f, myY2 = 0.f, myX2 = 0.f, myAr = 0.f;
    if (tid < KCAND) {
        u32 idx = ~(u32)x;
        float4 bx = ((const float4*)boxes)[(size_t)b * NANCH + idx];
        myY1 = bx.x; myX1 = bx.y; myY2 = bx.z; myX2 = bx.w;
        myAr = (bx.z - bx.x) * (bx.w - bx.y);
    } else {
        myV = 0.f;
    }
    __syncthreads();   // all LDS reads of sort/hist done before overlay write
    cbY1[tid] = myY1; cbX1[tid] = myX1; cbY2[tid] = myY2; cbX2[tid] = myX2;
    cbAr[tid] = myAr; cVal[tid] = myV;
    __syncthreads();

    // ---- 200x200 IoU bitmask via per-wave ballot ----
    const int lane = tid & 63;
    const int wv = tid >> 6;
#pragma unroll 2
    for (int i = 0; i < KCAND; ++i) {
        float y1i = cbY1[i], x1i = cbX1[i], y2i = cbY2[i], x2i = cbX2[i], ari = cbAr[i];
        bool hit = false;
        if (tid < KCAND) {
            float ih = fminf(y2i, myY2) - fmaxf(y1i, myY1);
            ih = fmaxf(ih, 0.0f);
            float iw = fminf(x2i, myX2) - fmaxf(x1i, myX1);
            iw = fmaxf(iw, 0.0f);
            float inter = ih * iw;
            float iou = inter / (ari + myAr - inter + 1e-8f);
            hit = iou > 0.5f;
        }
        u64 bal = __ballot(hit);
        if (lane == 0) iouM[i * 4 + wv] = bal;
    }
    __syncthreads();

    if (tid < PPC) outS[tid] = 0.0f;
    if (tid < PPC * 4) outB[tid] = 0.0f;
    __syncthreads();

    // ---- sequential NMS, 64-lane cooperative (wave 0) ----
    if (tid < 64) {
        u64 k0 = 0, k1 = 0, k2 = 0, k3 = 0;
#pragma unroll
        for (int chunk = 0; chunk < 4; ++chunk) {
            int i = chunk * 64 + tid;
            u64 r0 = 0, r1 = 0, r2 = 0, r3 = 0;
            bool vld = false;
            if (i < KCAND) {
                r0 = iouM[i * 4 + 0]; r1 = iouM[i * 4 + 1];
                r2 = iouM[i * 4 + 2]; r3 = iouM[i * 4 + 3];
                vld = cVal[i] > 0.5f;
            }
            int lim = KCAND - chunk * 64; if (lim > 64) lim = 64; if (lim < 0) lim = 0;
            for (int l = 0; l < lim; ++l) {
                int mydec = (vld && !((k0 & r0) | (k1 & r1) | (k2 & r2) | (k3 & r3))) ? 1 : 0;
                int d = __shfl(mydec, l, 64);
                if (d) {
                    u64 bit = 1ull << l;
                    if (chunk == 0) k0 |= bit; else if (chunk == 1) k1 |= bit;
                    else if (chunk == 2) k2 |= bit; else k3 |= bit;
                }
            }
        }
        // emit first 20 kept (== top_k(kept_scores, 20) since values sorted)
        int base = 0;
#pragma unroll
        for (int chunk = 0; chunk < 4; ++chunk) {
            u64 kw = (chunk == 0) ? k0 : (chunk == 1) ? k1 : (chunk == 2) ? k2 : k3;
            int i = chunk * 64 + tid;
            bool kept = ((kw >> tid) & 1ull) != 0;
            int rank = base + (int)__popcll(kw & ((1ull << tid) - 1ull));
            if (kept && rank < PPC && i < KCAND) {
                outS[rank] = cVal[i];
                outB[rank * 4 + 0] = cbY1[i];
                outB[rank * 4 + 1] = cbX1[i];
                outB[rank * 4 + 2] = cbY2[i];
                outB[rank * 4 + 3] = cbX2[i];
            }
            base += (int)__popcll(kw);
        }
    }
    __syncthreads();
    if (tid < PPC) clsScores[(size_t)bc * PPC + tid] = outS[tid];
    if (tid < PPC * 4) clsBoxes[(size_t)bc * PPC * 4 + tid] = outB[tid];
#undef FETCH_SCORE
}

// -------------------- Kernel C: merge 21*20 per batch -> top 20 --------------------
__global__ __launch_bounds__(512) void kmerge(
    const float* __restrict__ clsScores, const float* __restrict__ clsBoxes,
    float* __restrict__ out)
{
#pragma clang fp contract(off)
    __shared__ u64 key[512];
    const int tid = threadIdx.x;
    const int b = blockIdx.x;
    const int F = NCLS * PPC;  // 420
    u64 kk = 0;
    if (tid < F) {
        float v = clsScores[(size_t)b * F + tid];
        kk = ((u64)__float_as_uint(v) << 32) | (u32)(~(u32)tid);
    }
    key[tid] = kk;
    for (int k = 2; k <= 512; k <<= 1)
        for (int j = k >> 1; j > 0; j >>= 1) {
            __syncthreads();
            int ixj = tid ^ j;
            if (ixj > tid) {
                u64 a = key[tid], bb = key[ixj];
                if (((tid & k) == 0) ? (a < bb) : (a > bb)) { key[tid] = bb; key[ixj] = a; }
            }
        }
    __syncthreads();
    if (tid < PTOT) {
        u64 kx = key[tid];
        float v = __uint_as_float((u32)(kx >> 32));
        u32 f = ~((u32)kx);
        bool valid = (v > 0.0f) && (f < (u32)F);
        float cls = valid ? (float)(f / PPC) : 0.0f;
        float* oB = out;
        float* oV = out + (size_t)BATCH * PTOT * 4;
        float* oL = oV + (size_t)BATCH * PTOT;
#pragma unroll
        for (int q = 0; q < 4; ++q) {
            float xq = 0.0f;
            if (valid) {
                xq = clsBoxes[((size_t)b * F + f) * 4 + q];
                xq = fminf(fmaxf(xq, 0.0f), 1.0f);
            }
            oB[((size_t)b * PTOT + tid) * 4 + q] = xq;
        }
        oV[(size_t)b * PTOT + tid] = v;
        oL[(size_t)b * PTOT + tid] = cls;
    }
}

extern "C" void kernel_launch(void* const* d_in, const int* in_sizes, int n_in,
                              void* d_out, int out_size, void* d_ws, size_t ws_size,
                              hipStream_t stream)
{
    const float* deltas  = (const float*)d_in[0];
    const float* labels  = (const float*)d_in[1];
    const float* anchors = (const float*)d_in[2];
    float* out = (float*)d_out;
    char* ws = (char*)d_ws;

    // ws layout (all offsets 256B aligned)
    const size_t boxesOff = 0;           // B*N*4 f32 = 8,941,568 B
    const size_t maskOff  = 8941568;     // B*N u8   =   558,848 B
    const size_t csOff    = 9500416;     // B*C*20 f32 = 107,520 B
    const size_t cbOff    = 9607936;     // B*C*20*4 f32 = 430,080 B
    const size_t stOff    = 10038016;    // B*C*N f32 = 46,943,232 B (optional)
    const size_t needT    = 56981248;

    float* boxes = (float*)(ws + boxesOff);
    unsigned char* msk = (unsigned char*)(ws + maskOff);
    float* clsScores = (float*)(ws + csOff);
    float* clsBoxes  = (float*)(ws + cbOff);
    float* scoresT   = (float*)(ws + stOff);
    int useT = (ws_size >= needT) ? 1 : 0;
    if (!useT) scoresT = boxes;  // unused in that case

    dim3 gA((NANCH + 255) / 256, BATCH);
    kdecode<<<gA, 256, 0, stream>>>(deltas, labels, anchors, boxes, msk, scoresT, useT);
    knms<<<BATCH * NCLS, 256, 0, stream>>>(labels, msk, scoresT, boxes, clsScores, clsBoxes, useT);
    kmerge<<<BATCH, 512, 0, stream>>>(clsScores, clsBoxes, out);
}

// Round 3
// 70.771 us; speedup vs baseline: 3.2967x; 2.0368x over previous
//
#include <hip/hip_runtime.h>
#include <stdint.h>

typedef unsigned long long u64;
typedef unsigned int u32;

#define BATCH 64
#define NANCH 8732
#define NF4   2183      // NANCH/4 exactly
#define NCLS 21
#define KCAND 200
#define PPC 20
#define PTOT 20

// -------------------- Kernel A: argmax mask + decode + transpose --------------------
__global__ __launch_bounds__(256) void kdecode(
    const float* __restrict__ deltas, const float* __restrict__ labels,
    const float* __restrict__ anchors, float* __restrict__ boxes,
    unsigned char* __restrict__ msk, float* __restrict__ scoresT, int useT)
{
#pragma clang fp contract(off)
    int n = blockIdx.x * 256 + threadIdx.x;
    int b = blockIdx.y;
    if (n >= NANCH) return;
    const float* lab = labels + ((size_t)b * NANCH + n) * NCLS;
    float v[NCLS];
#pragma unroll
    for (int c = 0; c < NCLS; ++c) v[c] = lab[c];
    float mx = v[0]; int am = 0;
#pragma unroll
    for (int c = 1; c < NCLS; ++c) if (v[c] > mx) { mx = v[c]; am = c; }
    bool mk = (am != 0);
    msk[(size_t)b * NANCH + n] = mk ? 1 : 0;
    if (useT) {
#pragma unroll
        for (int c = 0; c < NCLS; ++c)
            scoresT[((size_t)b * NCLS + c) * NANCH + n] = mk ? v[c] : 0.0f;
    }
    float4 d = ((const float4*)deltas)[(size_t)b * NANCH + n];
    float4 a = ((const float4*)anchors)[n];
    float ah = a.z - a.x, aw = a.w - a.y;
    float acy = a.x + 0.5f * ah, acx = a.y + 0.5f * aw;
    float cy = (d.x * 0.1f) * ah + acy;
    float cx = (d.y * 0.1f) * aw + acx;
    float hh = expf(d.z * 0.2f) * ah;
    float ww = expf(d.w * 0.2f) * aw;
    float4 o;
    o.x = cy - 0.5f * hh; o.y = cx - 0.5f * ww;
    o.z = cy + 0.5f * hh; o.w = cx + 0.5f * ww;
    ((float4*)boxes)[(size_t)b * NANCH + n] = o;
}

__device__ __forceinline__ u64 shflxor64(u64 x, int m) {
    return (u64)__shfl_xor((long long)x, m, 64);
}

// Find bin where descending cumulative count crosses `need`.
// Precondition: sSel/sAbove/sH zeroed and a __syncthreads() executed after
// zeroing + hist fill. Postcondition: results visible (ends with barrier).
__device__ __forceinline__ void suffixFind(const u32* hist, u32* waveTot, int nb, int need,
                                           int* sSel, int* sAbove, int* sH,
                                           int tid, int lane, int wv)
{
    int K = (nb + 255) >> 8;
    int base = tid * K;
    u32 own = 0;
    for (int q = 0; q < K; ++q) { int bi = base + q; own += (bi < nb) ? hist[bi] : 0u; }
    u32 s = own;
#pragma unroll
    for (int d = 1; d < 64; d <<= 1) {
        u32 o = __shfl_down(s, d, 64);
        if (lane + d < 64) s += o;
    }
    if (lane == 0) waveTot[wv] = s;
    __syncthreads();
    u32 add = 0;
    for (int w = wv + 1; w < 4; ++w) add += waveTot[w];
    u32 cum = (s - own) + add;            // strictly above this thread's bins
    for (int q = K - 1; q >= 0; --q) {
        int bi = base + q;
        u32 hh = (bi < nb) ? hist[bi] : 0u;
        if (cum < (u32)need && cum + hh >= (u32)need) { *sSel = bi; *sAbove = (int)cum; *sH = (int)hh; }
        cum += hh;
    }
    __syncthreads();
}

// -------------------- Kernel B: per (b,c) top-200 + NMS + top-20 --------------------
__global__ __launch_bounds__(256) void knms(
    const float* __restrict__ labels, const unsigned char* __restrict__ msk,
    const float* __restrict__ scoresT, const float* __restrict__ boxes,
    float* __restrict__ clsScores, float* __restrict__ clsBoxes, int useT)
{
#pragma clang fp contract(off)
    // 8 KB overlay region: selection phase = hist[2048]; post phase = cb*/cVal/iouT
    __shared__ __align__(16) char smem[8192];
    u32*   hist = (u32*)smem;               // [2048]
    float* cbY1 = (float*)smem;             // [256]
    float* cbX1 = (float*)(smem + 1024);
    float* cbY2 = (float*)(smem + 2048);
    float* cbX2 = (float*)(smem + 3072);
    float* cbAr = (float*)(smem + 4096);
    float* cVal = (float*)(smem + 5120);
    u64*   iouT = (u64*)(smem + 6144);      // [64][4] = 2048 B
    __shared__ u64 candKey[256];
    __shared__ u32 waveTot[4];
    __shared__ float outS[PPC];
    __shared__ float outB[PPC * 4];
    __shared__ int sSel, sAbove, sH, sN, sKP;

    const int tid = threadIdx.x;
    const int lane = tid & 63;
    const int wv = tid >> 6;
    const int bc = blockIdx.x;
    const int b = bc / NCLS;
    const int c = bc % NCLS;

    // ---- load all 8732 scores into registers (9 float4 per thread) ----
    float4 rs[9];
    if (useT) {
        const float4* src4 = (const float4*)(scoresT + (size_t)bc * NANCH);
#pragma unroll
        for (int q = 0; q < 9; ++q) {
            int i4 = q * 256 + tid;
            rs[q] = (i4 < NF4) ? src4[i4] : make_float4(0.f, 0.f, 0.f, 0.f);
        }
    } else {
#pragma unroll
        for (int q = 0; q < 9; ++q) {
            float vv[4];
#pragma unroll
            for (int e = 0; e < 4; ++e) {
                int n = (q * 256 + tid) * 4 + e;
                float v = 0.f;
                if (n < NANCH && msk[(size_t)b * NANCH + n])
                    v = labels[((size_t)b * NANCH + n) * NCLS + c];
                vv[e] = v;
            }
            rs[q] = make_float4(vv[0], vv[1], vv[2], vv[3]);
        }
    }

    // ---- 2048-bin histogram of t>>13, t = trunc(v * 2^24) ----
    for (int q = tid; q < 2048; q += 256) hist[q] = 0;
    if (tid == 0) { sSel = 0; sAbove = 0; sH = 0; sN = 0; sKP = 0; }
    __syncthreads();
#pragma unroll
    for (int q = 0; q < 9; ++q) {
        if (q * 256 + tid < NF4) {
            float vv[4] = {rs[q].x, rs[q].y, rs[q].z, rs[q].w};
#pragma unroll
            for (int e = 0; e < 4; ++e) {
                u32 t = (u32)(vv[e] * 16777216.0f);
                atomicAdd(&hist[t >> 13], 1u);
            }
        }
    }
    __syncthreads();
    suffixFind(hist, waveTot, 2048, KCAND, &sSel, &sAbove, &sH, tid, lane, wv);
    int A = sAbove, h = sH;
    u32 T = (u32)sSel << 13;
    int cnt = A + h;

    // ---- exact refinement if threshold bin overflows 256-key buffer (rare) ----
    u32 width = 8192;
    for (int level = 0; level < 2 && cnt > 256; ++level) {
        int nb = (level == 0) ? 256 : 32;
        int shift = (level == 0) ? 5 : 0;
        for (int q = tid; q < nb; q += 256) hist[q] = 0;
        if (tid == 0) { sSel = 0; sAbove = 0; sH = 0; }
        __syncthreads();
#pragma unroll
        for (int q = 0; q < 9; ++q) {
            if (q * 256 + tid < NF4) {
                float vv[4] = {rs[q].x, rs[q].y, rs[q].z, rs[q].w};
#pragma unroll
                for (int e = 0; e < 4; ++e) {
                    u32 t = (u32)(vv[e] * 16777216.0f);
                    if (t >= T && t - T < width) atomicAdd(&hist[(t - T) >> shift], 1u);
                }
            }
        }
        __syncthreads();
        suffixFind(hist, waveTot, nb, KCAND - A, &sSel, &sAbove, &sH, tid, lane, wv);
        h = sH;
        A += sAbove;
        T += (u32)sSel << shift;
        cnt = A + h;
        width = 1u << shift;
    }

    // ---- compact all t >= T from registers (superset of exact top-200 incl. ties) ----
#pragma unroll
    for (int q = 0; q < 9; ++q) {
        if (q * 256 + tid < NF4) {
            float vv[4] = {rs[q].x, rs[q].y, rs[q].z, rs[q].w};
#pragma unroll
            for (int e = 0; e < 4; ++e) {
                float v = vv[e];
                u32 t = (u32)(v * 16777216.0f);
                if (t >= T) {
                    int slot = atomicAdd(&sN, 1);
                    if (slot < 256) {
                        int n = (q * 256 + tid) * 4 + e;
                        candKey[slot] = ((u64)__float_as_uint(v) << 32) | (u32)(~(u32)n);
                    }
                }
            }
        }
    }
    __syncthreads();
    int nc = sN; if (nc > 256) nc = 256;

    // ---- register bitonic sort desc on 256 keys (shfl_xor j<64, LDS j>=64) ----
    u64 x = (tid < nc) ? candKey[tid] : 0ull;
    for (int k = 2; k <= 256; k <<= 1) {
        for (int j = k >> 1; j > 0; j >>= 1) {
            u64 y;
            if (j < 64) {
                y = shflxor64(x, j);
            } else {
                __syncthreads();
                candKey[tid] = x;
                __syncthreads();
                y = candKey[tid ^ j];
            }
            bool keepMax = ((tid & k) == 0) == ((tid & j) == 0);
            u64 mx = (x > y) ? x : y;
            u64 mn = (x > y) ? y : x;
            x = keepMax ? mx : mn;
        }
    }
    // x = tid-th largest key (value desc, index asc) == exact top_k order

    // ---- extract + gather boxes ----
    float myV = __uint_as_float((u32)(x >> 32));
    float myY1 = 0.f, myX1 = 0.f, myY2 = 0.f, myX2 = 0.f, myAr = 0.f;
    if (tid < KCAND) {
        u32 idx = ~(u32)x;
        float4 bx = ((const float4*)boxes)[(size_t)b * NANCH + idx];
        myY1 = bx.x; myX1 = bx.y; myY2 = bx.z; myX2 = bx.w;
        myAr = (bx.z - bx.x) * (bx.w - bx.y);
    } else {
        myV = 0.f;
    }
    __syncthreads();   // selection-phase LDS reads done before overlay write
    cbY1[tid] = myY1; cbX1[tid] = myX1; cbY2[tid] = myY2; cbX2[tid] = myX2;
    cbAr[tid] = myAr; cVal[tid] = myV;

    // ---- tiled IoU + serial NMS with early exit at 20 kept ----
    u64 k0 = 0, k1 = 0, k2 = 0, k3 = 0;
    int KPw = 0;
    for (int t0 = 0; t0 < 4; ++t0) {
        __syncthreads();                  // cb/iouT ready or free; sKP visible
        if (sKP >= PPC) break;            // uniform across block
        int rowBase = t0 * 64;
        int rows = KCAND - rowBase; if (rows > 64) rows = 64;
        // IoU rows of this tile vs colgroups 0..t0, split over 4 waves
        for (int r = wv; r < rows; r += 4) {
            int i = rowBase + r;
            float y1i = cbY1[i], x1i = cbX1[i], y2i = cbY2[i], x2i = cbX2[i], ari = cbAr[i];
            for (int cg = 0; cg <= t0; ++cg) {
                int j = cg * 64 + lane;
                float ih = fminf(y2i, cbY2[j]) - fmaxf(y1i, cbY1[j]);
                ih = fmaxf(ih, 0.0f);
                float iw = fminf(x2i, cbX2[j]) - fmaxf(x1i, cbX1[j]);
                iw = fmaxf(iw, 0.0f);
                float inter = ih * iw;
                float iou = inter / (ari + cbAr[j] - inter + 1e-8f);
                u64 bal = __ballot(iou > 0.5f);
                if (lane == 0) iouT[r * 4 + cg] = bal;
            }
        }
        __syncthreads();                  // iouT ready
        if (tid < 64) {
            int i = rowBase + lane;
            u64 r0 = 0, r1 = 0, r2 = 0, r3 = 0;
            bool vld = false;
            if (lane < rows) {
                r0 = iouT[lane * 4 + 0]; r1 = iouT[lane * 4 + 1];
                r2 = iouT[lane * 4 + 2]; r3 = iouT[lane * 4 + 3];
                vld = cVal[i] > 0.5f;
            }
            // keep-mask words for colgroups > t0 are all-zero, so stale iouT
            // entries are harmless; (keep & row) enforces j < i implicitly.
            for (int l = 0; l < rows; ++l) {
                int mydec = (vld && !((k0 & r0) | (k1 & r1) | (k2 & r2) | (k3 & r3))) ? 1 : 0;
                int d = __shfl(mydec, l, 64);
                if (d) {
                    u64 bit = 1ull << l;
                    if (t0 == 0) k0 |= bit; else if (t0 == 1) k1 |= bit;
                    else if (t0 == 2) k2 |= bit; else k3 |= bit;
                    ++KPw;
                    if (KPw >= PPC) break;   // uniform within wave (d broadcast)
                }
            }
            if (tid == 0) sKP = KPw;
        }
    }
    __syncthreads();

    if (tid < PPC) outS[tid] = 0.0f;
    if (tid < PPC * 4) outB[tid] = 0.0f;
    __syncthreads();

    // ---- emit first 20 kept (== top_k(kept_scores, 20) since values sorted) ----
    if (tid < 64) {
        int base = 0;
#pragma unroll
        for (int chunk = 0; chunk < 4; ++chunk) {
            u64 kw = (chunk == 0) ? k0 : (chunk == 1) ? k1 : (chunk == 2) ? k2 : k3;
            int i = chunk * 64 + tid;
            bool kept = ((kw >> tid) & 1ull) != 0;
            int rank = base + (int)__popcll(kw & ((1ull << tid) - 1ull));
            if (kept && rank < PPC && i < KCAND) {
                outS[rank] = cVal[i];
                outB[rank * 4 + 0] = cbY1[i];
                outB[rank * 4 + 1] = cbX1[i];
                outB[rank * 4 + 2] = cbY2[i];
                outB[rank * 4 + 3] = cbX2[i];
            }
            base += (int)__popcll(kw);
        }
    }
    __syncthreads();
    if (tid < PPC) clsScores[(size_t)bc * PPC + tid] = outS[tid];
    if (tid < PPC * 4) clsBoxes[(size_t)bc * PPC * 4 + tid] = outB[tid];
}

// -------------------- Kernel C: merge 21*20 per batch -> top 20 --------------------
__global__ __launch_bounds__(512) void kmerge(
    const float* __restrict__ clsScores, const float* __restrict__ clsBoxes,
    float* __restrict__ out)
{
#pragma clang fp contract(off)
    __shared__ u64 key[512];
    const int tid = threadIdx.x;
    const int b = blockIdx.x;
    const int F = NCLS * PPC;  // 420
    u64 kk = 0;
    if (tid < F) {
        float v = clsScores[(size_t)b * F + tid];
        kk = ((u64)__float_as_uint(v) << 32) | (u32)(~(u32)tid);
    }
    key[tid] = kk;
    for (int k = 2; k <= 512; k <<= 1)
        for (int j = k >> 1; j > 0; j >>= 1) {
            __syncthreads();
            int ixj = tid ^ j;
            if (ixj > tid) {
                u64 a = key[tid], bb = key[ixj];
                if (((tid & k) == 0) ? (a < bb) : (a > bb)) { key[tid] = bb; key[ixj] = a; }
            }
        }
    __syncthreads();
    if (tid < PTOT) {
        u64 kx = key[tid];
        float v = __uint_as_float((u32)(kx >> 32));
        u32 f = ~((u32)kx);
        bool valid = (v > 0.0f) && (f < (u32)F);
        float cls = valid ? (float)(f / PPC) : 0.0f;
        float* oB = out;
        float* oV = out + (size_t)BATCH * PTOT * 4;
        float* oL = oV + (size_t)BATCH * PTOT;
#pragma unroll
        for (int q = 0; q < 4; ++q) {
            float xq = 0.0f;
            if (valid) {
                xq = clsBoxes[((size_t)b * F + f) * 4 + q];
                xq = fminf(fmaxf(xq, 0.0f), 1.0f);
            }
            oB[((size_t)b * PTOT + tid) * 4 + q] = xq;
        }
        oV[(size_t)b * PTOT + tid] = v;
        oL[(size_t)b * PTOT + tid] = cls;
    }
}

extern "C" void kernel_launch(void* const* d_in, const int* in_sizes, int n_in,
                              void* d_out, int out_size, void* d_ws, size_t ws_size,
                              hipStream_t stream)
{
    const float* deltas  = (const float*)d_in[0];
    const float* labels  = (const float*)d_in[1];
    const float* anchors = (const float*)d_in[2];
    float* out = (float*)d_out;
    char* ws = (char*)d_ws;

    // ws layout (all offsets 256B aligned)
    const size_t boxesOff = 0;           // B*N*4 f32 = 8,941,568 B
    const size_t maskOff  = 8941568;     // B*N u8   =   558,848 B
    const size_t csOff    = 9500416;     // B*C*20 f32 = 107,520 B
    const size_t cbOff    = 9607936;     // B*C*20*4 f32 = 430,080 B
    const size_t stOff    = 10038016;    // B*C*N f32 = 46,943,232 B (optional)
    const size_t needT    = 56981248;

    float* boxes = (float*)(ws + boxesOff);
    unsigned char* msk = (unsigned char*)(ws + maskOff);
    float* clsScores = (float*)(ws + csOff);
    float* clsBoxes  = (float*)(ws + cbOff);
    float* scoresT   = (float*)(ws + stOff);
    int useT = (ws_size >= needT) ? 1 : 0;
    if (!useT) scoresT = boxes;  // unused in that case

    dim3 gA((NANCH + 255) / 256, BATCH);
    kdecode<<<gA, 256, 0, stream>>>(deltas, labels, anchors, boxes, msk, scoresT, useT);
    knms<<<BATCH * NCLS, 256, 0, stream>>>(labels, msk, scoresT, boxes, clsScores, clsBoxes, useT);
    kmerge<<<BATCH, 512, 0, stream>>>(clsScores, clsBoxes, out);
}

// Round 4
// 57.945 us; speedup vs baseline: 4.0265x; 1.2213x over previous
//
#include <hip/hip_runtime.h>
#include <stdint.h>

typedef unsigned long long u64;
typedef unsigned int u32;
typedef unsigned short u16;

#define BATCH 64
#define NANCH 8732
#define NPAD  8736       // u16 storage padded per (b,c): divisible by 8
#define NCHUNK 1092      // NPAD/8 uint4 chunks
#define NCLS 21
#define KCAND 200
#define PPC 20
#define PTOT 20

// -------------------- Kernel A: argmax mask + u16-key transpose --------------------
__global__ __launch_bounds__(256) void kdecode(
    const float* __restrict__ labels,
    unsigned char* __restrict__ msk, u16* __restrict__ st16, int useT)
{
#pragma clang fp contract(off)
    int n = blockIdx.x * 256 + threadIdx.x;
    int b = blockIdx.y;
    if (n >= NPAD) return;
    if (n >= NANCH) {                       // padding slots: key 0 (never selected)
        if (useT) {
#pragma unroll
            for (int c = 0; c < NCLS; ++c)
                st16[((size_t)b * NCLS + c) * NPAD + n] = 0;
        }
        return;
    }
    const float* lab = labels + ((size_t)b * NANCH + n) * NCLS;
    float v[NCLS];
#pragma unroll
    for (int c = 0; c < NCLS; ++c) v[c] = lab[c];
    float mx = v[0]; int am = 0;
#pragma unroll
    for (int c = 1; c < NCLS; ++c) if (v[c] > mx) { mx = v[c]; am = c; }
    bool mk = (am != 0);
    msk[(size_t)b * NANCH + n] = mk ? 1 : 0;
    if (useT) {
#pragma unroll
        for (int c = 0; c < NCLS; ++c) {
            // t16 = floor(v*65536): exact (exponent shift), monotone in v, v in [0,1)
            u16 t = mk ? (u16)(u32)(v[c] * 65536.0f) : (u16)0;
            st16[((size_t)b * NCLS + c) * NPAD + n] = t;
        }
    }
}

__device__ __forceinline__ u64 shflxor64(u64 x, int m) {
    return (u64)__shfl_xor((long long)x, m, 64);
}

// Find bin where descending cumulative count crosses `need`; optionally total.
__device__ __forceinline__ void suffixFind(const u32* hist, u32* waveTot, int nb, int need,
                                           int* sSel, int* sAbove, int* sH, int* sTot,
                                           int tid, int lane, int wv)
{
    int K = (nb + 255) >> 8;
    int base = tid * K;
    u32 own = 0;
    for (int q = 0; q < K; ++q) { int bi = base + q; own += (bi < nb) ? hist[bi] : 0u; }
    u32 s = own;
#pragma unroll
    for (int d = 1; d < 64; d <<= 1) {
        u32 o = __shfl_down(s, d, 64);
        if (lane + d < 64) s += o;
    }
    if (lane == 0) waveTot[wv] = s;
    __syncthreads();
    if (tid == 0 && sTot) *sTot = (int)(waveTot[0] + waveTot[1] + waveTot[2] + waveTot[3]);
    u32 add = 0;
    for (int w = wv + 1; w < 4; ++w) add += waveTot[w];
    u32 cum = (s - own) + add;               // strictly above this thread's bins
    for (int q = K - 1; q >= 0; --q) {
        int bi = base + q;
        u32 hh = (bi < nb) ? hist[bi] : 0u;
        if (cum < (u32)need && cum + hh >= (u32)need) { *sSel = bi; *sAbove = (int)cum; *sH = (int)hh; }
        cum += hh;
    }
    __syncthreads();
}

// -------------------- Kernel B: per (b,c) top-200 + NMS + top-20 --------------------
__global__ __launch_bounds__(256) void knms(
    const float* __restrict__ labels, const unsigned char* __restrict__ msk,
    const u16* __restrict__ st16,
    const float* __restrict__ deltas, const float* __restrict__ anchors,
    float* __restrict__ clsScores, float* __restrict__ clsBoxes, int useT)
{
#pragma clang fp contract(off)
    // 8 KB overlay: selection = hist[2048]; post = cb*/cVal/iouT
    __shared__ __align__(16) char smem[8192];
    u32*   hist = (u32*)smem;
    float* cbY1 = (float*)smem;
    float* cbX1 = (float*)(smem + 1024);
    float* cbY2 = (float*)(smem + 2048);
    float* cbX2 = (float*)(smem + 3072);
    float* cbAr = (float*)(smem + 4096);
    float* cVal = (float*)(smem + 5120);
    u64*   iouT = (u64*)(smem + 6144);      // [64][4]
    __shared__ u64 candKey[256];
    __shared__ u32 waveTot[4];
    __shared__ float outS[PPC];
    __shared__ float outB[PPC * 4];
    __shared__ int sSel, sAbove, sH, sTot, sN, sKP;

    const int tid = threadIdx.x;
    const int lane = tid & 63;
    const int wv = tid >> 6;
    const int bc = blockIdx.x;
    const int b = bc / NCLS;
    const int c = bc % NCLS;

    // ---- load all u16 keys into registers (5 uint4 = 40 keys per thread) ----
    uint4 rc[5];
    if (useT) {
        const uint4* src = (const uint4*)(st16 + (size_t)bc * NPAD);
#pragma unroll
        for (int q = 0; q < 5; ++q) {
            int i4 = q * 256 + tid;
            rc[q] = (i4 < NCHUNK) ? src[i4] : make_uint4(0, 0, 0, 0);
        }
    } else {
        for (int q = 0; q < 5; ++q) {
            int chunk = q * 256 + tid;
            u32 w4[4] = {0, 0, 0, 0};
            if (chunk < NCHUNK) {
                for (int w = 0; w < 4; ++w)
                    for (int h = 0; h < 2; ++h) {
                        int n = chunk * 8 + w * 2 + h;
                        u32 t = 0;
                        if (n < NANCH && msk[(size_t)b * NANCH + n]) {
                            float v = labels[((size_t)b * NANCH + n) * NCLS + c];
                            t = (u32)(v * 65536.0f);
                        }
                        w4[w] |= t << (16 * h);
                    }
            }
            rc[q] = make_uint4(w4[0], w4[1], w4[2], w4[3]);
        }
    }

    // ---- histogram over bins [1024,2048) == t16 >= 0x8000 (v >= 0.5; rest inert) ----
    for (int q = tid; q < 1024; q += 256) hist[1024 + q] = 0;
    if (tid == 0) { sSel = -1; sAbove = 0; sH = 0; sTot = 0; sN = 0; sKP = 0; }
    __syncthreads();
#pragma unroll
    for (int q = 0; q < 5; ++q) {
        if (q * 256 + tid < NCHUNK) {
            u32 w4[4] = {rc[q].x, rc[q].y, rc[q].z, rc[q].w};
#pragma unroll
            for (int w = 0; w < 4; ++w) {
                u32 lo = w4[w] & 0xFFFFu, hi = w4[w] >> 16;
                if (lo & 0x8000u) atomicAdd(&hist[lo >> 5], 1u);
                if (hi & 0x8000u) atomicAdd(&hist[hi >> 5], 1u);
            }
        }
    }
    __syncthreads();
    suffixFind(hist + 1024, waveTot, 1024, KCAND, &sSel, &sAbove, &sH, &sTot, tid, lane, wv);

    int A, cnt; u32 T16;
    if (sTot < KCAND) { T16 = 32768u; A = 0; cnt = sTot; }   // take all >=0.5 (rest inert)
    else { A = sAbove; T16 = (u32)(1024 + sSel) << 5; cnt = A + sH; }

    // ---- exact-t16 refinement if coarse bin overflows buffer (practically never) ----
    if (cnt > 256) {
        if (tid < 32) hist[tid] = 0;
        if (tid == 0) { sSel = -1; sAbove = 0; sH = 0; }
        __syncthreads();
#pragma unroll
        for (int q = 0; q < 5; ++q) {
            if (q * 256 + tid < NCHUNK) {
                u32 w4[4] = {rc[q].x, rc[q].y, rc[q].z, rc[q].w};
#pragma unroll
                for (int w = 0; w < 4; ++w) {
                    u32 lo = w4[w] & 0xFFFFu, hi = w4[w] >> 16;
                    if (lo >= T16 && lo < T16 + 32) atomicAdd(&hist[lo - T16], 1u);
                    if (hi >= T16 && hi < T16 + 32) atomicAdd(&hist[hi - T16], 1u);
                }
            }
        }
        __syncthreads();
        suffixFind(hist, waveTot, 32, KCAND - A, &sSel, &sAbove, &sH, nullptr, tid, lane, wv);
        A += sAbove;
        T16 += (u32)sSel;
        cnt = A + sH;
    }

    // ---- compact t16 >= T16; recover exact f32 value from labels (bit-exact) ----
#pragma unroll
    for (int q = 0; q < 5; ++q) {
        int chunk = q * 256 + tid;
        if (chunk < NCHUNK) {
            u32 w4[4] = {rc[q].x, rc[q].y, rc[q].z, rc[q].w};
#pragma unroll
            for (int w = 0; w < 4; ++w) {
#pragma unroll
                for (int h = 0; h < 2; ++h) {
                    u32 t = (h == 0) ? (w4[w] & 0xFFFFu) : (w4[w] >> 16);
                    if (t >= T16) {      // t>=0x8000 excludes padding slots
                        int n = chunk * 8 + w * 2 + h;
                        float v = labels[((size_t)b * NANCH + n) * NCLS + c];
                        int slot = atomicAdd(&sN, 1);
                        if (slot < 256)
                            candKey[slot] = ((u64)__float_as_uint(v) << 32) | (u32)(~(u32)n);
                    }
                }
            }
        }
    }
    __syncthreads();
    int nc = sN; if (nc > 256) nc = 256;

    // ---- register bitonic sort desc on 256 keys (shfl_xor j<64, LDS j>=64) ----
    u64 x = (tid < nc) ? candKey[tid] : 0ull;
    for (int k = 2; k <= 256; k <<= 1) {
        for (int j = k >> 1; j > 0; j >>= 1) {
            u64 y;
            if (j < 64) {
                y = shflxor64(x, j);
            } else {
                __syncthreads();
                candKey[tid] = x;
                __syncthreads();
                y = candKey[tid ^ j];
            }
            bool keepMax = ((tid & k) == 0) == ((tid & j) == 0);
            u64 mx = (x > y) ? x : y;
            u64 mn = (x > y) ? y : x;
            x = keepMax ? mx : mn;
        }
    }
    // x = tid-th largest (value desc, index asc) == exact top_k order

    // ---- on-demand box decode for own candidate ----
    float myV = __uint_as_float((u32)(x >> 32));
    float myY1 = 0.f, myX1 = 0.f, myY2 = 0.f, myX2 = 0.f, myAr = 0.f;
    u32 idx = ~(u32)x;
    if (tid < KCAND && idx < (u32)NANCH) {
        float4 d = ((const float4*)deltas)[(size_t)b * NANCH + idx];
        float4 a = ((const float4*)anchors)[idx];
        float ah = a.z - a.x, aw = a.w - a.y;
        float acy = a.x + 0.5f * ah, acx = a.y + 0.5f * aw;
        float cy = (d.x * 0.1f) * ah + acy;
        float cx = (d.y * 0.1f) * aw + acx;
        float hh2 = expf(d.z * 0.2f) * ah;
        float ww2 = expf(d.w * 0.2f) * aw;
        myY1 = cy - 0.5f * hh2; myX1 = cx - 0.5f * ww2;
        myY2 = cy + 0.5f * hh2; myX2 = cx + 0.5f * ww2;
        myAr = (myY2 - myY1) * (myX2 - myX1);
    } else {
        myV = 0.f;
    }
    __syncthreads();   // selection-phase LDS reads done before overlay write
    cbY1[tid] = myY1; cbX1[tid] = myX1; cbY2[tid] = myY2; cbX2[tid] = myX2;
    cbAr[tid] = myAr; cVal[tid] = myV;

    // ---- tiled IoU + serial NMS with early exit at 20 kept ----
    u64 k0 = 0, k1 = 0, k2 = 0, k3 = 0;
    int KPw = 0;
    for (int t0 = 0; t0 < 4; ++t0) {
        __syncthreads();                  // cb/iouT ready or free; sKP visible
        if (sKP >= PPC) break;            // uniform across block
        int rowBase = t0 * 64;
        int rows = KCAND - rowBase; if (rows > 64) rows = 64;
        for (int r = wv; r < rows; r += 4) {
            int i = rowBase + r;
            float y1i = cbY1[i], x1i = cbX1[i], y2i = cbY2[i], x2i = cbX2[i], ari = cbAr[i];
            for (int cg = 0; cg <= t0; ++cg) {
                int j = cg * 64 + lane;
                float ih = fminf(y2i, cbY2[j]) - fmaxf(y1i, cbY1[j]);
                ih = fmaxf(ih, 0.0f);
                float iw = fminf(x2i, cbX2[j]) - fmaxf(x1i, cbX1[j]);
                iw = fmaxf(iw, 0.0f);
                float inter = ih * iw;
                float iou = inter / (ari + cbAr[j] - inter + 1e-8f);
                u64 bal = __ballot(iou > 0.5f);
                if (lane == 0) iouT[r * 4 + cg] = bal;
            }
        }
        __syncthreads();                  // iouT ready
        if (tid < 64) {
            int i = rowBase + lane;
            u64 r0 = 0, r1 = 0, r2 = 0, r3 = 0;
            bool vld = false;
            if (lane < rows) {
                r0 = iouT[lane * 4 + 0]; r1 = iouT[lane * 4 + 1];
                r2 = iouT[lane * 4 + 2]; r3 = iouT[lane * 4 + 3];
                vld = cVal[i] > 0.5f;
            }
            // keep-mask words for colgroups > t0 are all-zero -> stale iouT harmless;
            // (keep & row) enforces j < i implicitly.
            for (int l = 0; l < rows; ++l) {
                int mydec = (vld && !((k0 & r0) | (k1 & r1) | (k2 & r2) | (k3 & r3))) ? 1 : 0;
                int d = __shfl(mydec, l, 64);
                if (d) {
                    u64 bit = 1ull << l;
                    if (t0 == 0) k0 |= bit; else if (t0 == 1) k1 |= bit;
                    else if (t0 == 2) k2 |= bit; else k3 |= bit;
                    ++KPw;
                    if (KPw >= PPC) break;   // uniform within wave (d broadcast)
                }
            }
            if (tid == 0) sKP = KPw;
        }
    }
    __syncthreads();

    if (tid < PPC) outS[tid] = 0.0f;
    if (tid < PPC * 4) outB[tid] = 0.0f;
    __syncthreads();

    // ---- emit first 20 kept (== top_k(kept_scores, 20) since values sorted) ----
    if (tid < 64) {
        int base = 0;
#pragma unroll
        for (int chunk = 0; chunk < 4; ++chunk) {
            u64 kw = (chunk == 0) ? k0 : (chunk == 1) ? k1 : (chunk == 2) ? k2 : k3;
            int i = chunk * 64 + tid;
            bool kept = ((kw >> tid) & 1ull) != 0;
            int rank = base + (int)__popcll(kw & ((1ull << tid) - 1ull));
            if (kept && rank < PPC && i < KCAND) {
                outS[rank] = cVal[i];
                outB[rank * 4 + 0] = cbY1[i];
                outB[rank * 4 + 1] = cbX1[i];
                outB[rank * 4 + 2] = cbY2[i];
                outB[rank * 4 + 3] = cbX2[i];
            }
            base += (int)__popcll(kw);
        }
    }
    __syncthreads();
    if (tid < PPC) clsScores[(size_t)bc * PPC + tid] = outS[tid];
    if (tid < PPC * 4) clsBoxes[(size_t)bc * PPC * 4 + tid] = outB[tid];
}

// -------------------- Kernel C: merge 21*20 per batch -> top 20 --------------------
__global__ __launch_bounds__(512) void kmerge(
    const float* __restrict__ clsScores, const float* __restrict__ clsBoxes,
    float* __restrict__ out)
{
#pragma clang fp contract(off)
    __shared__ u64 key[512];
    const int tid = threadIdx.x;
    const int b = blockIdx.x;
    const int F = NCLS * PPC;  // 420
    u64 kk = 0;
    if (tid < F) {
        float v = clsScores[(size_t)b * F + tid];
        kk = ((u64)__float_as_uint(v) << 32) | (u32)(~(u32)tid);
    }
    key[tid] = kk;
    for (int k = 2; k <= 512; k <<= 1)
        for (int j = k >> 1; j > 0; j >>= 1) {
            __syncthreads();
            int ixj = tid ^ j;
            if (ixj > tid) {
                u64 a = key[tid], bb = key[ixj];
                if (((tid & k) == 0) ? (a < bb) : (a > bb)) { key[tid] = bb; key[ixj] = a; }
            }
        }
    __syncthreads();
    if (tid < PTOT) {
        u64 kx = key[tid];
        float v = __uint_as_float((u32)(kx >> 32));
        u32 f = ~((u32)kx);
        bool valid = (v > 0.0f) && (f < (u32)F);
        float cls = valid ? (float)(f / PPC) : 0.0f;
        float* oB = out;
        float* oV = out + (size_t)BATCH * PTOT * 4;
        float* oL = oV + (size_t)BATCH * PTOT;
#pragma unroll
        for (int q = 0; q < 4; ++q) {
            float xq = 0.0f;
            if (valid) {
                xq = clsBoxes[((size_t)b * F + f) * 4 + q];
                xq = fminf(fmaxf(xq, 0.0f), 1.0f);
            }
            oB[((size_t)b * PTOT + tid) * 4 + q] = xq;
        }
        oV[(size_t)b * PTOT + tid] = v;
        oL[(size_t)b * PTOT + tid] = cls;
    }
}

extern "C" void kernel_launch(void* const* d_in, const int* in_sizes, int n_in,
                              void* d_out, int out_size, void* d_ws, size_t ws_size,
                              hipStream_t stream)
{
    const float* deltas  = (const float*)d_in[0];
    const float* labels  = (const float*)d_in[1];
    const float* anchors = (const float*)d_in[2];
    float* out = (float*)d_out;
    char* ws = (char*)d_ws;

    // ws layout (256B aligned)
    const size_t mskOff = 0;         // B*N u8        =    558,848
    const size_t csOff  = 558848;    // B*C*20 f32    =    107,520
    const size_t cbOff  = 666368;    // B*C*20*4 f32  =    430,080
    const size_t stOff  = 1096448;   // B*C*NPAD u16  = 23,482,368
    const size_t needT  = 24578816;

    unsigned char* msk = (unsigned char*)(ws + mskOff);
    float* clsScores = (float*)(ws + csOff);
    float* clsBoxes  = (float*)(ws + cbOff);
    u16* st16        = (u16*)(ws + stOff);
    int useT = (ws_size >= needT) ? 1 : 0;

    dim3 gA((NPAD + 255) / 256, BATCH);
    kdecode<<<gA, 256, 0, stream>>>(labels, msk, st16, useT);
    knms<<<BATCH * NCLS, 256, 0, stream>>>(labels, msk, st16, deltas, anchors,
                                           clsScores, clsBoxes, useT);
    kmerge<<<BATCH, 512, 0, stream>>>(clsScores, clsBoxes, out);
}